// Round 9
// baseline (64.388 us; speedup 1.0000x reference)
//
#include <hip/hip_runtime.h>
#include <hip/hip_bf16.h>

// SparseProtoLinear: S=131072 tokens, D=64, P=8 experts.
// d_out = [y (S*64) | logits (S*8) | mask (S*8)], fp32.
//
// prep_w: fp32 W1/W2 -> bf16 image in d_ws (XOR-swizzled rows; W2 columns
//         permuted so GEMM2 A-frags read as b128).
// spl_main: 512 blocks x 256 thr (4 waves), 64 tokens/WAVE (4 n-frags).
//   Each W-fragment read feeds 4 token-groups (2x round 8) -> half the
//   LDS traffic per token + 4 independent MFMA chains per slice (ILP).
//   LDS addresses hoisted to 4 base VGPRs + immediates. wt table stored
//   transposed [p][token] -> conflict-free reads. 72KB LDS, 2 blocks/CU.
//   Expert loop unroll-1, restage experts 4-7 at p==4 (2 barriers).
//   GEMM1 swapped (W1 x X^T, mfma 16x16x32) -> silu*wt in-register ->
//   GEMM2 (mfma 16x16x16) accumulates into yacc. LDS epilogue for
//   full-cacheline y stores.

typedef __attribute__((ext_vector_type(8))) short short8;
typedef __attribute__((ext_vector_type(4))) short bf16x4;   // HIP owns `short4`
typedef __attribute__((ext_vector_type(4))) float f32x4;
typedef __attribute__((ext_vector_type(4))) unsigned int u32x4;
typedef __attribute__((ext_vector_type(2))) unsigned int u32x2;

#define NEXP 8
#define DH 64
#define BT 256          // tokens per block = 4 waves * 64
#define THREADS 256
#define OFF_WT 65536
#define LDS_BYTES (65536 + 8192)   // 4-expert W buffer + transposed wt table

__device__ __forceinline__ unsigned int f2bf(float f) {
    unsigned int u = __builtin_bit_cast(unsigned int, f);
    return (u + 0x7fffu + ((u >> 16) & 1u)) >> 16;  // RTNE (prep kernel only)
}
__device__ __forceinline__ short bfc(float f) {     // compiler-lowered convert
    return (short)__bfloat16_as_ushort(__float2bfloat16(f));
}

#if __has_builtin(__builtin_amdgcn_mfma_f32_16x16x16_bf16)
#define MFMA16(a, b, c) __builtin_amdgcn_mfma_f32_16x16x16_bf16(a, b, c, 0, 0, 0)
#else
#define MFMA16(a, b, c) __builtin_amdgcn_mfma_f32_16x16x16bf16_1k(a, b, c, 0, 0, 0)
#endif

typedef const unsigned int __attribute__((address_space(1)))* gas_u32p;
typedef unsigned int __attribute__((address_space(3)))* las_u32p;

__device__ __forceinline__ void glds16(const void* g, void* lbase, int lane) {
#if __has_builtin(__builtin_amdgcn_global_load_lds)
    (void)lane;
    __builtin_amdgcn_global_load_lds((gas_u32p)g, (las_u32p)lbase, 16, 0, 0);
#else
    *reinterpret_cast<u32x4*>(reinterpret_cast<char*>(lbase) + lane * 16) =
        *reinterpret_cast<const u32x4*>(g);
#endif
}

// ---------------- prep: weights -> bf16 swizzled image (128 KiB) ----------------
__global__ void prep_w(const float* __restrict__ w1, const float* __restrict__ w2,
                       unsigned char* __restrict__ ws) {
    int q = blockIdx.x * 256 + threadIdx.x;          // 16384 quads of 4 f32
    int mat = q >> 13;                               // 0=W1, 1=W2
    int p = (q >> 10) & 7;
    int r = (q >> 4) & 63;                           // source row (o for W1, d for W2)
    int dq = q & 15;                                 // source col quad
    const float* src = (mat ? w2 : w1) + (size_t)(((p << 6) + r) << 6) + (dq << 2);
    f32x4 v = *reinterpret_cast<const f32x4*>(src);
    u32x2 pk;
    pk[0] = f2bf(v[0]) | (f2bf(v[1]) << 16);
    pk[1] = f2bf(v[2]) | (f2bf(v[3]) << 16);
    // W1: byte col = dq*8.  W2 col-permute o=[mp|fg|j]->[fg|mp|j]:
    //   mp=dq>>2, fg=dq&3 -> byte col = fg*32 + mp*8.
    int col = mat ? (((dq & 3) << 5) | ((dq >> 2) << 3)) : (dq << 3);
    int off = (p << 14) + (mat << 13) + (r << 7) + (col ^ ((r & 7) << 4));
    *reinterpret_cast<u32x2*>(ws + off) = pk;
}

// ---------------- main fused kernel ----------------
__global__ __launch_bounds__(THREADS, 1)   // no VGPR cap (spill is worse)
void spl_main(const float* __restrict__ x, const float* __restrict__ proto,
              const float* __restrict__ gate, const unsigned char* __restrict__ wimg,
              float* __restrict__ y_out, float* __restrict__ logits_out,
              float* __restrict__ mask_out)
{
    extern __shared__ __align__(16) char smem[];     // [0,64K) W | [64K,72K) wt^T
    const int tid = threadIdx.x;
    const int lane = tid & 63;
    const int wv = __builtin_amdgcn_readfirstlane(tid >> 6);
    const int fr = lane & 15;
    const int fg = (lane >> 4) & 3;
    const int sw = (fr & 7) << 4;
    const int t0 = blockIdx.x * BT + wv * 64;        // wave-local 64 tokens

    // stage 4 experts (64KB) of pass `ps` (4 waves x 16 chunks of 1KB)
    auto stage = [&](int ps) {
#pragma unroll
        for (int i = 0; i < 16; ++i) {
            const int ch = (i * 4 + wv) << 10;
            glds16(wimg + (ps << 16) + ch + lane * 16, smem + ch, lane);
        }
    };

    // ---- Phase A: X load + logits/mask + wt^T table (NO DMA in flight) ----
    float xv[4][2][8];
#pragma unroll
    for (int n = 0; n < 4; ++n)
#pragma unroll
        for (int kk = 0; kk < 2; ++kk) {
            const float* g = x + (size_t)(t0 + n * 16 + fr) * DH + kk * 32 + fg * 8;
            f32x4 a = *reinterpret_cast<const f32x4*>(g);
            f32x4 b = *reinterpret_cast<const f32x4*>(g + 4);
#pragma unroll
            for (int i = 0; i < 4; ++i) { xv[n][kk][i] = a[i]; xv[n][kk][4 + i] = b[i]; }
        }
    {
        float dot[4][NEXP];
#pragma unroll
        for (int n = 0; n < 4; ++n)
#pragma unroll
            for (int p = 0; p < NEXP; ++p) dot[n][p] = 0.f;
#pragma unroll
        for (int p = 0; p < NEXP; ++p)
#pragma unroll
            for (int kk = 0; kk < 2; ++kk) {
                const float* pr = proto + p * DH + kk * 32 + fg * 8;
                f32x4 p0 = *reinterpret_cast<const f32x4*>(pr);
                f32x4 p1 = *reinterpret_cast<const f32x4*>(pr + 4);
#pragma unroll
                for (int n = 0; n < 4; ++n)
#pragma unroll
                    for (int i = 0; i < 4; ++i)
                        dot[n][p] += xv[n][kk][i] * p0[i] + xv[n][kk][4 + i] * p1[i];
            }
        // butterfly each (n,p) over the 4 fg groups; lane keeps n == fg
        float lgs[NEXP], mks[NEXP];
#pragma unroll
        for (int p = 0; p < NEXP; ++p) {
            float s0 = dot[0][p], s1 = dot[1][p], s2 = dot[2][p], s3 = dot[3][p];
            s0 += __shfl_xor(s0, 16); s0 += __shfl_xor(s0, 32);
            s1 += __shfl_xor(s1, 16); s1 += __shfl_xor(s1, 32);
            s2 += __shfl_xor(s2, 16); s2 += __shfl_xor(s2, 32);
            s3 += __shfl_xor(s3, 16); s3 += __shfl_xor(s3, 32);
            float sel = (fg & 2) ? ((fg & 1) ? s3 : s2) : ((fg & 1) ? s1 : s0);
            float l = sel * 0.125f - gate[p];        // / sqrt(64)
            lgs[p] = l;
            mks[p] = fmaxf(l, 0.f);
        }
        // lane (fr,fg) owns token row fg*16+fr: store logits+mask, wt^T -> LDS
        size_t rowb = (size_t)(t0 + fg * 16 + fr) * NEXP;
        f32x4 v0, v1;
#pragma unroll
        for (int i = 0; i < 4; ++i) { v0[i] = lgs[i]; v1[i] = lgs[4 + i]; }
        *reinterpret_cast<f32x4*>(logits_out + rowb) = v0;
        *reinterpret_cast<f32x4*>(logits_out + rowb + 4) = v1;
#pragma unroll
        for (int i = 0; i < 4; ++i) { v0[i] = mks[i]; v1[i] = mks[4 + i]; }
        *reinterpret_cast<f32x4*>(mask_out + rowb) = v0;
        *reinterpret_cast<f32x4*>(mask_out + rowb + 4) = v1;
#pragma unroll
        for (int p = 0; p < NEXP; ++p) {
            float w = (mks[p] > 1e-6f) ? mks[p] : 0.f;
            *reinterpret_cast<float*>(
                smem + OFF_WT + (p << 10) + (wv * 64 + fg * 16 + fr) * 4) = w;
        }
    }

    // ---- stage pass-0 weights; pack X->bf16 under the DMA ----
    stage(0);
    short8 xb[4][2];
#pragma unroll
    for (int n = 0; n < 4; ++n)
#pragma unroll
        for (int kk = 0; kk < 2; ++kk) {
            short8 t;
#pragma unroll
            for (int j = 0; j < 8; ++j) t[j] = bfc(xv[n][kk][j]);
            xb[n][kk] = t;
        }
    __syncthreads();                                 // W pass-0 + wt table visible

    f32x4 yacc[4][4];                                // [mt][n]
#pragma unroll
    for (int mt = 0; mt < 4; ++mt)
#pragma unroll
        for (int n = 0; n < 4; ++n) yacc[mt][n] = (f32x4){0.f, 0.f, 0.f, 0.f};

    // hoisted lane addresses (expert/h/mtl/kk deltas are immediates)
    const int aW1k0 = fr * 128 + ((fg * 16) ^ sw);
    const int aW1k1 = fr * 128 + ((64 + fg * 16) ^ sw);
    const int aW2h0 = 8192 + fr * 128 + ((fg * 32) ^ sw);
    const int aW2h1 = 8192 + fr * 128 + ((16 + fg * 32) ^ sw);
    const int awt = OFF_WT + (wv * 64 + fr) * 4;     // + p<<10 + n*64

#pragma unroll 1
    for (int p = 0; p < NEXP; ++p) {
        if (p == 4) {                                // restage experts 4-7
            __syncthreads();
            stage(1);
            __syncthreads();
        }
        char* const eb = smem + ((p & 3) << 14);
        float wtn[4];
#pragma unroll
        for (int n = 0; n < 4; ++n)
            wtn[n] = *reinterpret_cast<const float*>(smem + awt - OFF_WT + OFF_WT +
                                                     (p << 10) + n * 64);
#pragma unroll
        for (int h = 0; h < 2; ++h) {                // o-halves
            short8 w1f[2][2];
#pragma unroll
            for (int mtl = 0; mtl < 2; ++mtl) {
                const int ro = (h * 32 + mtl * 16) * 128;
                w1f[mtl][0] = *reinterpret_cast<const short8*>(eb + aW1k0 + ro);
                w1f[mtl][1] = *reinterpret_cast<const short8*>(eb + aW1k1 + ro);
            }
            f32x4 acc1[2][4];
#pragma unroll
            for (int mtl = 0; mtl < 2; ++mtl)
#pragma unroll
                for (int n = 0; n < 4; ++n) acc1[mtl][n] = (f32x4){0.f, 0.f, 0.f, 0.f};
#pragma unroll
            for (int kk = 0; kk < 2; ++kk)
#pragma unroll
                for (int mtl = 0; mtl < 2; ++mtl)
#pragma unroll
                    for (int n = 0; n < 4; ++n)
                        acc1[mtl][n] = __builtin_amdgcn_mfma_f32_16x16x32_bf16(
                            w1f[mtl][kk], xb[n][kk], acc1[mtl][n], 0, 0, 0);

            // silu * wt -> bf16 (GEMM2 B-frag layout, in-register)
            bf16x4 pkB[2][4];
#pragma unroll
            for (int mtl = 0; mtl < 2; ++mtl)
#pragma unroll
                for (int n = 0; n < 4; ++n) {
                    bf16x4 t;
#pragma unroll
                    for (int r = 0; r < 4; ++r) {
                        float hd = acc1[mtl][n][r];
                        float s = hd * __builtin_amdgcn_rcpf(1.f + __expf(-hd));
                        t[r] = bfc(wtn[n] * s);
                    }
                    pkB[mtl][n] = t;
                }

            // GEMM2 k-slices mp = 2h, 2h+1 accumulate straight into yacc
            const int aW2 = h ? aW2h1 : aW2h0;
#pragma unroll
            for (int mt = 0; mt < 4; ++mt) {
                u32x4 wq = *reinterpret_cast<const u32x4*>(eb + aW2 + mt * 16 * 128);
                u32x2 lo2 = {wq[0], wq[1]}, hi2 = {wq[2], wq[3]};
                bf16x4 wlo = __builtin_bit_cast(bf16x4, lo2);
                bf16x4 whi = __builtin_bit_cast(bf16x4, hi2);
#pragma unroll
                for (int n = 0; n < 4; ++n) {
                    yacc[mt][n] = MFMA16(wlo, pkB[0][n], yacc[mt][n]);
                    yacc[mt][n] = MFMA16(whi, pkB[1][n], yacc[mt][n]);
                }
            }
        }
    }

    // ---- epilogue: yacc -> LDS (W region dead) -> full-line y stores ----
    __syncthreads();                                 // all waves done with W
    char* const yb = smem + wv * 16384;              // 64 rows x 256B per wave
#pragma unroll
    for (int mt = 0; mt < 4; ++mt)
#pragma unroll
        for (int n = 0; n < 4; ++n) {
            f32x4 v;
#pragma unroll
            for (int r = 0; r < 4; ++r) v[r] = yacc[mt][n][r];
            *reinterpret_cast<f32x4*>(
                yb + (n * 16 + fr) * 256 + ((mt * 64 + fg * 16) ^ sw)) = v;
        }
    __builtin_amdgcn_s_waitcnt(0);                   // lgkm drain (per-wave region)
#pragma unroll
    for (int it = 0; it < 16; ++it) {
        const int r = it * 4 + (lane >> 4);          // row 0..63
        const int cb = (lane & 15) * 16;             // col byte within 256B row
        f32x4 v = *reinterpret_cast<const f32x4*>(yb + r * 256 + (cb ^ ((r & 7) << 4)));
        *reinterpret_cast<f32x4*>(
            reinterpret_cast<char*>(y_out) + (size_t)(t0 + r) * 256 + cb) = v;
    }
}

extern "C" void kernel_launch(void* const* d_in, const int* in_sizes, int n_in,
                              void* d_out, int out_size, void* d_ws, size_t ws_size,
                              hipStream_t stream) {
    (void)n_in; (void)out_size; (void)ws_size;
    const float* x     = (const float*)d_in[0];
    const float* proto = (const float*)d_in[1];
    const float* gate  = (const float*)d_in[2];
    const float* w1    = (const float*)d_in[3];
    const float* w2    = (const float*)d_in[4];
    float* y = (float*)d_out;
    const int S = in_sizes[0] / DH;                  // 131072
    float* logits = y + (size_t)S * DH;
    float* mask   = logits + (size_t)S * NEXP;
    unsigned char* wimg = (unsigned char*)d_ws;      // 128 KiB image

    prep_w<<<64, 256, 0, stream>>>(w1, w2, wimg);
    (void)hipFuncSetAttribute(reinterpret_cast<const void*>(spl_main),
                              hipFuncAttributeMaxDynamicSharedMemorySize, LDS_BYTES);
    spl_main<<<S / BT, THREADS, LDS_BYTES, stream>>>(x, proto, gate, wimg,
                                                     y, logits, mask);
}